// Round 5
// baseline (222.318 us; speedup 1.0000x reference)
//
#include <hip/hip_runtime.h>

// Fused: X->QKV proj (fp16 MFMA) -> RoPE -> GQA causal flash attn -> out proj.
// B=2 T=2048 D=2048 NQ=16 NK=4 H=128, scale=1.0 (no 1/sqrt(H)).

typedef _Float16 half8 __attribute__((ext_vector_type(8)));
typedef _Float16 half4 __attribute__((ext_vector_type(4)));
typedef float f32x4 __attribute__((ext_vector_type(4)));

#define GLOAD16(gp, lp) \
  __builtin_amdgcn_global_load_lds((__attribute__((address_space(1))) void*)(gp), \
                                   (__attribute__((address_space(3))) void*)(lp), 16, 0, 0)

#define WAIT_VM8() asm volatile("s_waitcnt vmcnt(8)" ::: "memory")
#define WAIT_VM0() asm volatile("s_waitcnt vmcnt(0)" ::: "memory")
#define BAR() asm volatile("s_barrier" ::: "memory")

static constexpr int T_   = 2048;
static constexpr int D_   = 2048;
static constexpr int NQ_  = 16;
static constexpr int NK_  = 4;
static constexpr int H_   = 128;
static constexpr int NQKV = 3072;   // 16*128 + 4*128 + 4*128
static constexpr int KOFF = 2048;
static constexpr int VOFF = 2560;

// ---------------- prep kernels ----------------

__global__ void cast_x_kernel(const float* __restrict__ in, _Float16* __restrict__ out) {
  int i = (blockIdx.x * 256 + threadIdx.x) * 4;
  float4 v = *reinterpret_cast<const float4*>(in + i);
  union { _Float16 h[4]; uint2 u; } p;
  p.h[0] = (_Float16)v.x; p.h[1] = (_Float16)v.y;
  p.h[2] = (_Float16)v.z; p.h[3] = (_Float16)v.w;
  *reinterpret_cast<uint2*>(out + i) = p.u;
}

// in: [2048][ncols] f32  ->  out: [ncols][2048] f16 (row stride 2048)
__global__ void transpose_cast_kernel(const float* __restrict__ in,
                                      _Float16* __restrict__ out, int ncols) {
  __shared__ float tile[32][33];
  int n0 = blockIdx.x * 32, k0 = blockIdx.y * 32;
  int tx = threadIdx.x, ty = threadIdx.y;
#pragma unroll
  for (int i = 0; i < 32; i += 8)
    tile[ty + i][tx] = in[(size_t)(k0 + ty + i) * ncols + (n0 + tx)];
  __syncthreads();
#pragma unroll
  for (int i = 0; i < 32; i += 8)
    out[(size_t)(n0 + ty + i) * 2048 + (k0 + tx)] = (_Float16)tile[tx][ty + i];
}

// RoPE in-place on Q (heads 0..15) and K (heads 16..19) sections of QKV buf.
__global__ void rope_kernel(_Float16* __restrict__ qkv, const int* __restrict__ pos) {
  int idx = blockIdx.x * 256 + threadIdx.x;   // < 4096*20*64
  int h = idx & 63;
  int head = (idx >> 6) % 20;
  int m = idx / (64 * 20);
  float p = (float)pos[m];
  float freq = expf(-0.14391156831f * (float)h);   // 10000^(-h/64)
  float a = p * freq;
  float s, c;
  sincosf(a, &s, &c);
  int col = (head < 16) ? (head * H_ + h) : (KOFF + (head - 16) * H_ + h);
  _Float16* ptr = qkv + (size_t)m * NQKV + col;
  float x1 = (float)ptr[0], x2 = (float)ptr[64];
  ptr[0]  = (_Float16)(x1 * c - x2 * s);
  ptr[64] = (_Float16)(x2 * c + x1 * s);
}

// V section of QKV [m][2560+kh*128+h] -> Vt [b][kh][h][t]
__global__ void vtrans_kernel(const _Float16* __restrict__ qkv, _Float16* __restrict__ vt) {
  __shared__ _Float16 tile[32][33];
  int t0 = blockIdx.x * 32, h0 = blockIdx.y * 32;
  int slab = blockIdx.z;  // b*4 + kh
  int tx = threadIdx.x, ty = threadIdx.y;
  int b = slab >> 2, kh = slab & 3;
#pragma unroll
  for (int i = 0; i < 32; i += 8)
    tile[ty + i][tx] = qkv[(size_t)(b * T_ + t0 + ty + i) * NQKV + VOFF + kh * H_ + h0 + tx];
  __syncthreads();
#pragma unroll
  for (int i = 0; i < 32; i += 8)
    vt[(size_t)(slab * H_ + h0 + ty + i) * T_ + (t0 + tx)] = tile[tx][ty + i];
}

// ---------------- GEMM: C[M,N] = A[M,K] * Bt[N,K]^T ----------------
// 128x128 tile, BK=64, 4 waves (2x2), 4x4 16x16x32 frags/wave.
// LDS XOR-swizzle (unit ^= row&7) via pre-swizzled global source (rule 21).

template <int OUT_F32>
__global__ __launch_bounds__(256, 2) void gemm_kernel(const _Float16* __restrict__ A,
                                                      const _Float16* __restrict__ Bt,
                                                      void* __restrict__ Cout, int N, int K) {
  __shared__ __align__(16) _Float16 As[128 * 64];
  __shared__ __align__(16) _Float16 Bs[128 * 64];
  const int tid = threadIdx.x;
  const int wave = tid >> 6, lane = tid & 63;
  const int lg = lane >> 4, lm = lane & 15;
  const int brow = blockIdx.y * 128, bcol = blockIdx.x * 128;
  const int wr = wave >> 1, wc = wave & 1;
  f32x4 acc[4][4] = {};
  for (int k0 = 0; k0 < K; k0 += 64) {
#pragma unroll
    for (int j = 0; j < 4; ++j) {
      int U = j * 256 + tid;          // 16B unit index, 8 units/row
      int row = U >> 3, u = U & 7;
      int us = u ^ (row & 7);
      GLOAD16(A + (size_t)(brow + row) * K + k0 + us * 8, (char*)As + ((j * 256 + wave * 64) << 4));
      GLOAD16(Bt + (size_t)(bcol + row) * K + k0 + us * 8, (char*)Bs + ((j * 256 + wave * 64) << 4));
    }
    __syncthreads();
#pragma unroll
    for (int kk = 0; kk < 2; ++kk) {
      half8 af[4], bf[4];
#pragma unroll
      for (int m = 0; m < 4; ++m) {
        int row = wr * 64 + m * 16 + lm;
        int u = (kk * 4 + lg) ^ (row & 7);
        af[m] = *reinterpret_cast<const half8*>(As + row * 64 + u * 8);
      }
#pragma unroll
      for (int n = 0; n < 4; ++n) {
        int row = wc * 64 + n * 16 + lm;
        int u = (kk * 4 + lg) ^ (row & 7);
        bf[n] = *reinterpret_cast<const half8*>(Bs + row * 64 + u * 8);
      }
#pragma unroll
      for (int m = 0; m < 4; ++m)
#pragma unroll
        for (int n = 0; n < 4; ++n)
          acc[m][n] = __builtin_amdgcn_mfma_f32_16x16x32_f16(af[m], bf[n], acc[m][n], 0, 0, 0);
    }
    __syncthreads();
  }
#pragma unroll
  for (int m = 0; m < 4; ++m)
#pragma unroll
    for (int n = 0; n < 4; ++n)
#pragma unroll
      for (int r = 0; r < 4; ++r) {
        size_t row = brow + wr * 64 + m * 16 + lg * 4 + r;
        size_t col = bcol + wc * 64 + n * 16 + lm;
        if constexpr (OUT_F32) ((float*)Cout)[row * N + col] = acc[m][n][r];
        else ((_Float16*)Cout)[row * N + col] = (_Float16)acc[m][n][r];
      }
}

// ---------------- flash attention ----------------
// Wave owns 32 q-rows (mq=2): each kf/vf LDS read feeds 2 MFMAs (halves the
// LDS-pipe cost per q-row; the kernel was LDS-pipe-bound). Block = 128 q-rows,
// paired q-tiles (p, 15-p) -> uniform 34 KV-iterations. 256 blocks = 1/CU;
// XCD chunk of 32 = one (b,kh) K/V set. Swapped QK^T, exp2 units, defer-max.

__global__ __launch_bounds__(256, 1) void attn_kernel(const _Float16* __restrict__ qkv,
                                                      const _Float16* __restrict__ vt,
                                                      _Float16* __restrict__ attn) {
  __shared__ __align__(16) _Float16 Ks[2][64 * 128];    // [s][h], 16 units/row, u^= s&15
  __shared__ __align__(16) _Float16 Vs[2][128 * 64];    // [h][s],  8 units/row, u^= h&7
  __shared__ __align__(16) _Float16 Ps[4][32 * 64];     // per-wave [q][s], u^= q&7
  const int bid = blockIdx.x;
  const int swz = (bid & 7) * 32 + (bid >> 3);          // XCD chunk = 32 consecutive swz
  const int chunk = swz >> 5;                           // = b*4 + kh
  const int b = chunk >> 2, kh = chunk & 3;
  const int n = kh * 4 + ((swz >> 3) & 3);
  const int p = swz & 7;                                // pair index: tiles p, 15-p
  const int tid = threadIdx.x, wave = tid >> 6, lane = tid & 63;
  const int lg = lane >> 4, lm = lane & 15;

  auto stage = [&](int j, int buf) {
    const int s0 = j * 64;
    char* Kb = (char*)&Ks[buf][0];
    char* Vb = (char*)&Vs[buf][0];
#pragma unroll
    for (int jj = 0; jj < 4; ++jj) {   // K tile: 64 rows x 16 units
      int U = jj * 256 + tid;
      int srow = U >> 4, u = U & 15;
      int us = u ^ (srow & 15);
      GLOAD16(qkv + (size_t)(b * T_ + s0 + srow) * NQKV + KOFF + kh * H_ + us * 8,
              Kb + ((jj * 256 + wave * 64) << 4));
    }
#pragma unroll
    for (int jj = 0; jj < 4; ++jj) {   // Vt tile: 128 rows x 8 units
      int U = jj * 256 + tid;
      int hrow = U >> 3, u = U & 7;
      int us = u ^ (hrow & 7);
      GLOAD16(vt + (size_t)((b * NK_ + kh) * H_ + hrow) * T_ + s0 + us * 8,
              Vb + ((jj * 256 + wave * 64) << 4));
    }
  };

  for (int ph = 0; ph < 2; ++ph) {
    const int t = ph ? (15 - p) : p;                    // q-tile, rows [128t, 128t+127]
    const int qbase = t * 128 + wave * 32;

    // Q fragments (2 row-sets of 16), scaled by log2(e) -> logits in log2 units.
    half8 qf[2][4];
#pragma unroll
    for (int mq = 0; mq < 2; ++mq) {
      const _Float16* qptr = qkv + (size_t)(b * T_ + qbase + mq * 16 + lm) * NQKV + n * H_;
#pragma unroll
      for (int kk = 0; kk < 4; ++kk) {
        half8 qr = *reinterpret_cast<const half8*>(qptr + kk * 32 + lg * 8);
#pragma unroll
        for (int j = 0; j < 8; ++j)
          qf[mq][kk][j] = (_Float16)((float)qr[j] * 1.4426950408889634f);
      }
    }

    f32x4 o[2][8] = {};
    float mrow[2] = {-1e30f, -1e30f}, lrow[2] = {0.f, 0.f};

    const int nkv = 2 * t + 2;
    stage(0, 0);
    for (int it = 0; it < nkv; ++it) {
      const int cur = it & 1;
      if (it + 1 < nkv) { stage(it + 1, cur ^ 1); WAIT_VM8(); }
      else              { WAIT_VM0(); }
      BAR();
      const _Float16* Kt = &Ks[cur][0];
      const _Float16* Vt2 = &Vs[cur][0];

      // Swapped QK^T: S[mq][ns][r] = logit(q = qbase+mq*16+lm, s = it*64+ns*16+lg*4+r)
      f32x4 S[2][4];
      __builtin_amdgcn_s_setprio(1);
#pragma unroll
      for (int ns = 0; ns < 4; ++ns) {
        half8 kf[4];
        int srow = ns * 16 + lm;
#pragma unroll
        for (int kk = 0; kk < 4; ++kk) {
          int u = (kk * 4 + lg) ^ (srow & 15);
          kf[kk] = *reinterpret_cast<const half8*>(Kt + srow * 128 + u * 8);
        }
#pragma unroll
        for (int mq = 0; mq < 2; ++mq) {
          f32x4 a = {0.f, 0.f, 0.f, 0.f};
#pragma unroll
          for (int kk = 0; kk < 4; ++kk)
            a = __builtin_amdgcn_mfma_f32_16x16x32_f16(kf[kk], qf[mq][kk], a, 0, 0, 0);
          S[mq][ns] = a;
        }
      }
      __builtin_amdgcn_s_setprio(0);

      if (it >= 2 * t) {              // diagonal-overlap tiles: causal mask
#pragma unroll
        for (int mq = 0; mq < 2; ++mq) {
          const int q = qbase + mq * 16 + lm;
#pragma unroll
          for (int ns = 0; ns < 4; ++ns)
#pragma unroll
            for (int r = 0; r < 4; ++r) {
              int s = it * 64 + ns * 16 + lg * 4 + r;
              if (s > q) S[mq][ns][r] = -1e30f;
            }
        }
      }

      // Row max per mq: 15 local fmax + 2 shfl (xor16/xor32 share the q-row).
      float pm[2];
#pragma unroll
      for (int mq = 0; mq < 2; ++mq) {
        float a0 = fmaxf(fmaxf(S[mq][0][0], S[mq][0][1]), fmaxf(S[mq][0][2], S[mq][0][3]));
        float a1 = fmaxf(fmaxf(S[mq][1][0], S[mq][1][1]), fmaxf(S[mq][1][2], S[mq][1][3]));
        float a2 = fmaxf(fmaxf(S[mq][2][0], S[mq][2][1]), fmaxf(S[mq][2][2], S[mq][2][3]));
        float a3 = fmaxf(fmaxf(S[mq][3][0], S[mq][3][1]), fmaxf(S[mq][3][2], S[mq][3][3]));
        float v = fmaxf(fmaxf(a0, a1), fmaxf(a2, a3));
        v = fmaxf(v, __shfl_xor(v, 16));
        v = fmaxf(v, __shfl_xor(v, 32));
        pm[mq] = v;
      }

      // Defer-max: rescale only when some row's max grew past THR (log2 units).
      if (__any(pm[0] > mrow[0] + 14.f || pm[1] > mrow[1] + 14.f)) {
#pragma unroll
        for (int mq = 0; mq < 2; ++mq) {
          float mn = fmaxf(mrow[mq], pm[mq]);
          float sc = __builtin_amdgcn_exp2f(mrow[mq] - mn);
          mrow[mq] = mn;
          lrow[mq] *= sc;
          float scr[4];
#pragma unroll
          for (int r = 0; r < 4; ++r) scr[r] = __shfl(sc, lg * 4 + r);
#pragma unroll
          for (int nh = 0; nh < 8; ++nh)
#pragma unroll
            for (int r = 0; r < 4; ++r) o[mq][nh][r] *= scr[r];
        }
      }

#pragma unroll
      for (int mq = 0; mq < 2; ++mq) {
        const float m = mrow[mq];
        float ps = 0.f;
#pragma unroll
        for (int ns = 0; ns < 4; ++ns)
#pragma unroll
          for (int r = 0; r < 4; ++r) {
            float pv = __builtin_amdgcn_exp2f(S[mq][ns][r] - m);
            S[mq][ns][r] = pv;
            ps += pv;
          }
        ps += __shfl_xor(ps, 16);
        ps += __shfl_xor(ps, 32);
        lrow[mq] += ps;

        // P -> LDS: 4x ds_write_b64 (packed half4), XOR swizzle matching PA read.
        const int qq = mq * 16 + lm;
#pragma unroll
        for (int ns = 0; ns < 4; ++ns) {
          half4 pk;
#pragma unroll
          for (int r = 0; r < 4; ++r) pk[r] = (_Float16)S[mq][ns][r];
          int u = (2 * ns + (lg >> 1)) ^ (lm & 7);
          *reinterpret_cast<half4*>(&Ps[wave][qq * 64 + u * 8 + (lg & 1) * 4]) = pk;
        }
      }

      __builtin_amdgcn_s_setprio(1);
#pragma unroll
      for (int kk2 = 0; kk2 < 2; ++kk2) {
        half8 pa[2];
#pragma unroll
        for (int mq = 0; mq < 2; ++mq) {
          int up = (kk2 * 4 + lg) ^ (lm & 7);
          pa[mq] = *reinterpret_cast<const half8*>(&Ps[wave][(mq * 16 + lm) * 64 + up * 8]);
        }
#pragma unroll
        for (int nh = 0; nh < 8; ++nh) {
          int hrow = nh * 16 + lm;
          int u = (kk2 * 4 + lg) ^ (hrow & 7);
          half8 vf = *reinterpret_cast<const half8*>(Vt2 + hrow * 64 + u * 8);
#pragma unroll
          for (int mq = 0; mq < 2; ++mq)
            o[mq][nh] = __builtin_amdgcn_mfma_f32_16x16x32_f16(pa[mq], vf, o[mq][nh], 0, 0, 0);
        }
      }
      __builtin_amdgcn_s_setprio(0);
      BAR();
    }

#pragma unroll
    for (int mq = 0; mq < 2; ++mq) {
      float linv[4];
#pragma unroll
      for (int r = 0; r < 4; ++r) linv[r] = 1.f / __shfl(lrow[mq], lg * 4 + r);
#pragma unroll
      for (int r = 0; r < 4; ++r) {
        int q = qbase + mq * 16 + lg * 4 + r;
        _Float16* optr = attn + ((size_t)(b * T_ + q) * NQ_ + n) * H_ + lm;
#pragma unroll
        for (int nh = 0; nh < 8; ++nh)
          optr[nh * 16] = (_Float16)(o[mq][nh][r] * linv[r]);
      }
    }
  }
}

// ---------------- launch ----------------

extern "C" void kernel_launch(void* const* d_in, const int* in_sizes, int n_in,
                              void* d_out, int out_size, void* d_ws, size_t ws_size,
                              hipStream_t stream) {
  const float* X  = (const float*)d_in[0];
  const int* pos  = (const int*)d_in[1];
  const float* Wq = (const float*)d_in[2];
  const float* Wk = (const float*)d_in[3];
  const float* Wv = (const float*)d_in[4];
  const float* Wo = (const float*)d_in[5];

  _Float16* Xh    = (_Float16*)d_ws;                   // 4096*2048
  _Float16* Wqkvt = Xh + (size_t)4096 * 2048;          // [3072][2048]
  _Float16* Wot   = Wqkvt + (size_t)3072 * 2048;       // [2048][2048]
  _Float16* QKV   = Wot + (size_t)2048 * 2048;         // [4096][3072]
  _Float16* Vt    = QKV + (size_t)4096 * 3072;         // [2][4][128][2048]
  _Float16* Attn  = Vt + (size_t)8 * 128 * 2048;       // [4096][2048]

  dim3 tb(32, 8);
  cast_x_kernel<<<8192, 256, 0, stream>>>(X, Xh);
  transpose_cast_kernel<<<dim3(64, 64), tb, 0, stream>>>(Wq, Wqkvt, 2048);
  transpose_cast_kernel<<<dim3(16, 64), tb, 0, stream>>>(Wk, Wqkvt + (size_t)2048 * 2048, 512);
  transpose_cast_kernel<<<dim3(16, 64), tb, 0, stream>>>(Wv, Wqkvt + (size_t)2560 * 2048, 512);
  transpose_cast_kernel<<<dim3(64, 64), tb, 0, stream>>>(Wo, Wot, 2048);

  gemm_kernel<0><<<dim3(24, 32), 256, 0, stream>>>(Xh, Wqkvt, QKV, NQKV, 2048);
  rope_kernel<<<20480, 256, 0, stream>>>(QKV, pos);
  vtrans_kernel<<<dim3(64, 4, 8), tb, 0, stream>>>(QKV, Vt);
  attn_kernel<<<256, 256, 0, stream>>>(QKV, Vt, Attn);
  gemm_kernel<1><<<dim3(16, 32), 256, 0, stream>>>(Attn, Wot, d_out, 2048, 2048);
}

// Round 6
// 213.670 us; speedup vs baseline: 1.0405x; 1.0405x over previous
//
#include <hip/hip_runtime.h>

// Fused: X->QKV proj (fp16 MFMA) -> RoPE -> GQA causal flash attn -> out proj.
// B=2 T=2048 D=2048 NQ=16 NK=4 H=128, scale=1.0 (no 1/sqrt(H)).

typedef _Float16 half8 __attribute__((ext_vector_type(8)));
typedef _Float16 half4 __attribute__((ext_vector_type(4)));
typedef float f32x4 __attribute__((ext_vector_type(4)));

#define GLOAD16(gp, lp) \
  __builtin_amdgcn_global_load_lds((__attribute__((address_space(1))) void*)(gp), \
                                   (__attribute__((address_space(3))) void*)(lp), 16, 0, 0)

#define WAIT_VM8() asm volatile("s_waitcnt vmcnt(8)" ::: "memory")
#define WAIT_VM0() asm volatile("s_waitcnt vmcnt(0)" ::: "memory")
#define BAR() asm volatile("s_barrier" ::: "memory")

static constexpr int T_   = 2048;
static constexpr int D_   = 2048;
static constexpr int NQ_  = 16;
static constexpr int NK_  = 4;
static constexpr int H_   = 128;
static constexpr int NQKV = 3072;   // 16*128 + 4*128 + 4*128
static constexpr int KOFF = 2048;
static constexpr int VOFF = 2560;

// ---------------- prep kernels ----------------

__global__ void cast_x_kernel(const float* __restrict__ in, _Float16* __restrict__ out) {
  int i = (blockIdx.x * 256 + threadIdx.x) * 4;
  float4 v = *reinterpret_cast<const float4*>(in + i);
  union { _Float16 h[4]; uint2 u; } p;
  p.h[0] = (_Float16)v.x; p.h[1] = (_Float16)v.y;
  p.h[2] = (_Float16)v.z; p.h[3] = (_Float16)v.w;
  *reinterpret_cast<uint2*>(out + i) = p.u;
}

// in: [2048][ncols] f32  ->  out: [ncols][2048] f16 (row stride 2048)
__global__ void transpose_cast_kernel(const float* __restrict__ in,
                                      _Float16* __restrict__ out, int ncols) {
  __shared__ float tile[32][33];
  int n0 = blockIdx.x * 32, k0 = blockIdx.y * 32;
  int tx = threadIdx.x, ty = threadIdx.y;
#pragma unroll
  for (int i = 0; i < 32; i += 8)
    tile[ty + i][tx] = in[(size_t)(k0 + ty + i) * ncols + (n0 + tx)];
  __syncthreads();
#pragma unroll
  for (int i = 0; i < 32; i += 8)
    out[(size_t)(n0 + ty + i) * 2048 + (k0 + tx)] = (_Float16)tile[tx][ty + i];
}

// RoPE in-place on Q (heads 0..15) and K (heads 16..19) sections of QKV buf.
__global__ void rope_kernel(_Float16* __restrict__ qkv, const int* __restrict__ pos) {
  int idx = blockIdx.x * 256 + threadIdx.x;   // < 4096*20*64
  int h = idx & 63;
  int head = (idx >> 6) % 20;
  int m = idx / (64 * 20);
  float p = (float)pos[m];
  float freq = expf(-0.14391156831f * (float)h);   // 10000^(-h/64)
  float a = p * freq;
  float s, c;
  sincosf(a, &s, &c);
  int col = (head < 16) ? (head * H_ + h) : (KOFF + (head - 16) * H_ + h);
  _Float16* ptr = qkv + (size_t)m * NQKV + col;
  float x1 = (float)ptr[0], x2 = (float)ptr[64];
  ptr[0]  = (_Float16)(x1 * c - x2 * s);
  ptr[64] = (_Float16)(x2 * c + x1 * s);
}

// V section of QKV [m][2560+kh*128+h] -> Vt [b][kh][h][t]
__global__ void vtrans_kernel(const _Float16* __restrict__ qkv, _Float16* __restrict__ vt) {
  __shared__ _Float16 tile[32][33];
  int t0 = blockIdx.x * 32, h0 = blockIdx.y * 32;
  int slab = blockIdx.z;  // b*4 + kh
  int tx = threadIdx.x, ty = threadIdx.y;
  int b = slab >> 2, kh = slab & 3;
#pragma unroll
  for (int i = 0; i < 32; i += 8)
    tile[ty + i][tx] = qkv[(size_t)(b * T_ + t0 + ty + i) * NQKV + VOFF + kh * H_ + h0 + tx];
  __syncthreads();
#pragma unroll
  for (int i = 0; i < 32; i += 8)
    vt[(size_t)(slab * H_ + h0 + ty + i) * T_ + (t0 + tx)] = tile[tx][ty + i];
}

// ---------------- GEMM: C[M,N] = A[M,K] * Bt[N,K]^T ----------------
// 128x128 tile, BK=64, 4 waves (2x2), 4x4 16x16x32 frags/wave.
// LDS XOR-swizzle (unit ^= row&7) via pre-swizzled global source (rule 21).

template <int OUT_F32>
__global__ __launch_bounds__(256, 2) void gemm_kernel(const _Float16* __restrict__ A,
                                                      const _Float16* __restrict__ Bt,
                                                      void* __restrict__ Cout, int N, int K) {
  __shared__ __align__(16) _Float16 As[128 * 64];
  __shared__ __align__(16) _Float16 Bs[128 * 64];
  const int tid = threadIdx.x;
  const int wave = tid >> 6, lane = tid & 63;
  const int lg = lane >> 4, lm = lane & 15;
  const int brow = blockIdx.y * 128, bcol = blockIdx.x * 128;
  const int wr = wave >> 1, wc = wave & 1;
  f32x4 acc[4][4] = {};
  for (int k0 = 0; k0 < K; k0 += 64) {
#pragma unroll
    for (int j = 0; j < 4; ++j) {
      int U = j * 256 + tid;          // 16B unit index, 8 units/row
      int row = U >> 3, u = U & 7;
      int us = u ^ (row & 7);
      GLOAD16(A + (size_t)(brow + row) * K + k0 + us * 8, (char*)As + ((j * 256 + wave * 64) << 4));
      GLOAD16(Bt + (size_t)(bcol + row) * K + k0 + us * 8, (char*)Bs + ((j * 256 + wave * 64) << 4));
    }
    __syncthreads();
#pragma unroll
    for (int kk = 0; kk < 2; ++kk) {
      half8 af[4], bf[4];
#pragma unroll
      for (int m = 0; m < 4; ++m) {
        int row = wr * 64 + m * 16 + lm;
        int u = (kk * 4 + lg) ^ (row & 7);
        af[m] = *reinterpret_cast<const half8*>(As + row * 64 + u * 8);
      }
#pragma unroll
      for (int n = 0; n < 4; ++n) {
        int row = wc * 64 + n * 16 + lm;
        int u = (kk * 4 + lg) ^ (row & 7);
        bf[n] = *reinterpret_cast<const half8*>(Bs + row * 64 + u * 8);
      }
#pragma unroll
      for (int m = 0; m < 4; ++m)
#pragma unroll
        for (int n = 0; n < 4; ++n)
          acc[m][n] = __builtin_amdgcn_mfma_f32_16x16x32_f16(af[m], bf[n], acc[m][n], 0, 0, 0);
    }
    __syncthreads();
  }
#pragma unroll
  for (int m = 0; m < 4; ++m)
#pragma unroll
    for (int n = 0; n < 4; ++n)
#pragma unroll
      for (int r = 0; r < 4; ++r) {
        size_t row = brow + wr * 64 + m * 16 + lg * 4 + r;
        size_t col = bcol + wc * 64 + n * 16 + lm;
        if constexpr (OUT_F32) ((float*)Cout)[row * N + col] = acc[m][n][r];
        else ((_Float16*)Cout)[row * N + col] = (_Float16)acc[m][n][r];
      }
}

// ---------------- flash attention ----------------
// Wave owns 32 q-rows (mq=2); block = 128 q-rows; grid 512 = 2 blocks/CU
// (80KB LDS x2 = 160KB, VGPR<256 -> 2 waves/SIMD for latency hiding).
// Scheduler-level pairing: within each XCD 64-block chunk, slot-0 blocks get
// tiles t ascending, slot-1 blocks get 15-t, so co-resident pairs sum to a
// uniform 34 iterations (perf heuristic only). Swapped QK^T, exp2, defer-max.

__global__ __launch_bounds__(256, 2) void attn_kernel(const _Float16* __restrict__ qkv,
                                                      const _Float16* __restrict__ vt,
                                                      _Float16* __restrict__ attn) {
  __shared__ __align__(16) _Float16 Ks[2][64 * 128];    // [s][h], 16 units/row, u^= s&15
  __shared__ __align__(16) _Float16 Vs[2][128 * 64];    // [h][s],  8 units/row, u^= h&7
  __shared__ __align__(16) _Float16 Ps[4][32 * 64];     // per-wave [q][s], u^= q&7
  const int bid = blockIdx.x;
  const int swz = (bid & 7) * 64 + (bid >> 3);          // XCD chunk = 64 consecutive swz
  const int chunk = swz >> 6;                           // = b*4 + kh
  const int b = chunk >> 2, kh = chunk & 3;
  const int j64 = swz & 63;
  const int h2 = (j64 < 32) ? (j64 >> 4) : (2 + ((j64 - 32) >> 4));
  const int t  = (j64 < 32) ? (j64 & 15) : (15 - (j64 & 15));
  const int n = kh * 4 + h2;
  const int tid = threadIdx.x, wave = tid >> 6, lane = tid & 63;
  const int lg = lane >> 4, lm = lane & 15;
  const int qbase = t * 128 + wave * 32;

  auto stage = [&](int j, int buf) {
    const int s0 = j * 64;
    char* Kb = (char*)&Ks[buf][0];
    char* Vb = (char*)&Vs[buf][0];
#pragma unroll
    for (int jj = 0; jj < 4; ++jj) {   // K tile: 64 rows x 16 units
      int U = jj * 256 + tid;
      int srow = U >> 4, u = U & 15;
      int us = u ^ (srow & 15);
      GLOAD16(qkv + (size_t)(b * T_ + s0 + srow) * NQKV + KOFF + kh * H_ + us * 8,
              Kb + ((jj * 256 + wave * 64) << 4));
    }
#pragma unroll
    for (int jj = 0; jj < 4; ++jj) {   // Vt tile: 128 rows x 8 units
      int U = jj * 256 + tid;
      int hrow = U >> 3, u = U & 7;
      int us = u ^ (hrow & 7);
      GLOAD16(vt + (size_t)((b * NK_ + kh) * H_ + hrow) * T_ + s0 + us * 8,
              Vb + ((jj * 256 + wave * 64) << 4));
    }
  };

  // Q fragments (2 row-sets of 16), scaled by log2(e) -> logits in log2 units.
  half8 qf[2][4];
#pragma unroll
  for (int mq = 0; mq < 2; ++mq) {
    const _Float16* qptr = qkv + (size_t)(b * T_ + qbase + mq * 16 + lm) * NQKV + n * H_;
#pragma unroll
    for (int kk = 0; kk < 4; ++kk) {
      half8 qr = *reinterpret_cast<const half8*>(qptr + kk * 32 + lg * 8);
#pragma unroll
      for (int j = 0; j < 8; ++j)
        qf[mq][kk][j] = (_Float16)((float)qr[j] * 1.4426950408889634f);
    }
  }

  f32x4 o[2][8] = {};
  float mrow[2] = {-1e30f, -1e30f}, lrow[2] = {0.f, 0.f};

  const int nkv = 2 * t + 2;
  stage(0, 0);
  for (int it = 0; it < nkv; ++it) {
    const int cur = it & 1;
    if (it + 1 < nkv) { stage(it + 1, cur ^ 1); WAIT_VM8(); }
    else              { WAIT_VM0(); }
    BAR();
    const _Float16* Kt = &Ks[cur][0];
    const _Float16* Vt2 = &Vs[cur][0];

    // Swapped QK^T: S[mq][ns][r] = logit(q = qbase+mq*16+lm, s = it*64+ns*16+lg*4+r)
    f32x4 S[2][4];
    __builtin_amdgcn_s_setprio(1);
#pragma unroll
    for (int ns = 0; ns < 4; ++ns) {
      half8 kf[4];
      int srow = ns * 16 + lm;
#pragma unroll
      for (int kk = 0; kk < 4; ++kk) {
        int u = (kk * 4 + lg) ^ (srow & 15);
        kf[kk] = *reinterpret_cast<const half8*>(Kt + srow * 128 + u * 8);
      }
#pragma unroll
      for (int mq = 0; mq < 2; ++mq) {
        f32x4 a = {0.f, 0.f, 0.f, 0.f};
#pragma unroll
        for (int kk = 0; kk < 4; ++kk)
          a = __builtin_amdgcn_mfma_f32_16x16x32_f16(kf[kk], qf[mq][kk], a, 0, 0, 0);
        S[mq][ns] = a;
      }
    }
    __builtin_amdgcn_s_setprio(0);

    if (it >= 2 * t) {              // diagonal-overlap tiles: causal mask
#pragma unroll
      for (int mq = 0; mq < 2; ++mq) {
        const int q = qbase + mq * 16 + lm;
#pragma unroll
        for (int ns = 0; ns < 4; ++ns)
#pragma unroll
          for (int r = 0; r < 4; ++r) {
            int s = it * 64 + ns * 16 + lg * 4 + r;
            if (s > q) S[mq][ns][r] = -1e30f;
          }
      }
    }

    // Row max per mq: 15 local fmax + 2 shfl (xor16/xor32 share the q-row).
    float pm[2];
#pragma unroll
    for (int mq = 0; mq < 2; ++mq) {
      float a0 = fmaxf(fmaxf(S[mq][0][0], S[mq][0][1]), fmaxf(S[mq][0][2], S[mq][0][3]));
      float a1 = fmaxf(fmaxf(S[mq][1][0], S[mq][1][1]), fmaxf(S[mq][1][2], S[mq][1][3]));
      float a2 = fmaxf(fmaxf(S[mq][2][0], S[mq][2][1]), fmaxf(S[mq][2][2], S[mq][2][3]));
      float a3 = fmaxf(fmaxf(S[mq][3][0], S[mq][3][1]), fmaxf(S[mq][3][2], S[mq][3][3]));
      float v = fmaxf(fmaxf(a0, a1), fmaxf(a2, a3));
      v = fmaxf(v, __shfl_xor(v, 16));
      v = fmaxf(v, __shfl_xor(v, 32));
      pm[mq] = v;
    }

    // Defer-max: rescale only when some row's max grew past THR (log2 units).
    if (__any(pm[0] > mrow[0] + 14.f || pm[1] > mrow[1] + 14.f)) {
#pragma unroll
      for (int mq = 0; mq < 2; ++mq) {
        float mn = fmaxf(mrow[mq], pm[mq]);
        float sc = __builtin_amdgcn_exp2f(mrow[mq] - mn);
        mrow[mq] = mn;
        lrow[mq] *= sc;
        float scr[4];
#pragma unroll
        for (int r = 0; r < 4; ++r) scr[r] = __shfl(sc, lg * 4 + r);
#pragma unroll
        for (int nh = 0; nh < 8; ++nh)
#pragma unroll
          for (int r = 0; r < 4; ++r) o[mq][nh][r] *= scr[r];
      }
    }

#pragma unroll
    for (int mq = 0; mq < 2; ++mq) {
      const float m = mrow[mq];
      float ps = 0.f;
#pragma unroll
      for (int ns = 0; ns < 4; ++ns)
#pragma unroll
        for (int r = 0; r < 4; ++r) {
          float pv = __builtin_amdgcn_exp2f(S[mq][ns][r] - m);
          S[mq][ns][r] = pv;
          ps += pv;
        }
      ps += __shfl_xor(ps, 16);
      ps += __shfl_xor(ps, 32);
      lrow[mq] += ps;

      // P -> LDS: 4x ds_write_b64 (packed half4), XOR swizzle matching PA read.
      const int qq = mq * 16 + lm;
#pragma unroll
      for (int ns = 0; ns < 4; ++ns) {
        half4 pk;
#pragma unroll
        for (int r = 0; r < 4; ++r) pk[r] = (_Float16)S[mq][ns][r];
        int u = (2 * ns + (lg >> 1)) ^ (lm & 7);
        *reinterpret_cast<half4*>(&Ps[wave][qq * 64 + u * 8 + (lg & 1) * 4]) = pk;
      }
    }

    __builtin_amdgcn_s_setprio(1);
#pragma unroll
    for (int kk2 = 0; kk2 < 2; ++kk2) {
      half8 pa[2];
#pragma unroll
      for (int mq = 0; mq < 2; ++mq) {
        int up = (kk2 * 4 + lg) ^ (lm & 7);
        pa[mq] = *reinterpret_cast<const half8*>(&Ps[wave][(mq * 16 + lm) * 64 + up * 8]);
      }
#pragma unroll
      for (int nh = 0; nh < 8; ++nh) {
        int hrow = nh * 16 + lm;
        int u = (kk2 * 4 + lg) ^ (hrow & 7);
        half8 vf = *reinterpret_cast<const half8*>(Vt2 + hrow * 64 + u * 8);
#pragma unroll
        for (int mq = 0; mq < 2; ++mq)
          o[mq][nh] = __builtin_amdgcn_mfma_f32_16x16x32_f16(pa[mq], vf, o[mq][nh], 0, 0, 0);
      }
    }
    __builtin_amdgcn_s_setprio(0);
    BAR();
  }

#pragma unroll
  for (int mq = 0; mq < 2; ++mq) {
    float linv[4];
#pragma unroll
    for (int r = 0; r < 4; ++r) linv[r] = 1.f / __shfl(lrow[mq], lg * 4 + r);
#pragma unroll
    for (int r = 0; r < 4; ++r) {
      int q = qbase + mq * 16 + lg * 4 + r;
      _Float16* optr = attn + ((size_t)(b * T_ + q) * NQ_ + n) * H_ + lm;
#pragma unroll
      for (int nh = 0; nh < 8; ++nh)
        optr[nh * 16] = (_Float16)(o[mq][nh][r] * linv[r]);
    }
  }
}

// ---------------- launch ----------------

extern "C" void kernel_launch(void* const* d_in, const int* in_sizes, int n_in,
                              void* d_out, int out_size, void* d_ws, size_t ws_size,
                              hipStream_t stream) {
  const float* X  = (const float*)d_in[0];
  const int* pos  = (const int*)d_in[1];
  const float* Wq = (const float*)d_in[2];
  const float* Wk = (const float*)d_in[3];
  const float* Wv = (const float*)d_in[4];
  const float* Wo = (const float*)d_in[5];

  _Float16* Xh    = (_Float16*)d_ws;                   // 4096*2048
  _Float16* Wqkvt = Xh + (size_t)4096 * 2048;          // [3072][2048]
  _Float16* Wot   = Wqkvt + (size_t)3072 * 2048;       // [2048][2048]
  _Float16* QKV   = Wot + (size_t)2048 * 2048;         // [4096][3072]
  _Float16* Vt    = QKV + (size_t)4096 * 3072;         // [2][4][128][2048]
  _Float16* Attn  = Vt + (size_t)8 * 128 * 2048;       // [4096][2048]

  dim3 tb(32, 8);
  cast_x_kernel<<<8192, 256, 0, stream>>>(X, Xh);
  transpose_cast_kernel<<<dim3(64, 64), tb, 0, stream>>>(Wq, Wqkvt, 2048);
  transpose_cast_kernel<<<dim3(16, 64), tb, 0, stream>>>(Wk, Wqkvt + (size_t)2048 * 2048, 512);
  transpose_cast_kernel<<<dim3(16, 64), tb, 0, stream>>>(Wv, Wqkvt + (size_t)2560 * 2048, 512);
  transpose_cast_kernel<<<dim3(64, 64), tb, 0, stream>>>(Wo, Wot, 2048);

  gemm_kernel<0><<<dim3(24, 32), 256, 0, stream>>>(Xh, Wqkvt, QKV, NQKV, 2048);
  rope_kernel<<<20480, 256, 0, stream>>>(QKV, pos);
  vtrans_kernel<<<dim3(64, 4, 8), tb, 0, stream>>>(QKV, Vt);
  attn_kernel<<<512, 256, 0, stream>>>(QKV, Vt, Attn);
  gemm_kernel<1><<<dim3(16, 32), 256, 0, stream>>>(Attn, Wot, d_out, 2048, 2048);
}